// Round 5
// baseline (884.688 us; speedup 1.0000x reference)
//
#include <hip/hip_runtime.h>

// GPR-GNN: out = b_fc + sum_k temp[k] * A_hat^k (MLP(x) @ W_fc)
// Trick 1: project features to scalar BEFORE propagation (linearity) -> 1 float/node.
// Trick 2: per-edge atomics are LDS-only (global RMW ~35B/edge, measured R2/R3).
// Trick 3: u-space propagation u_k = D^{-1/2} z_k -> per-edge work = gather+add.
// Trick 4: bucketing = two-level counting sort (98 super-buckets of 1024 nodes).
// Trick 6: PUSH-accumulate hops, edges sorted by src super-bucket within each
//          dst bucket -> gathers sweep u in small L1-resident windows. With
//          bucket-major grid (block = 8b+chunk), XCD x gets chunk x of every
//          bucket -> each XCD re-gathers the SAME ~50KB u-slice (XCD-L2 hot).
// Trick 8 (R5, from measured 417.8us vs predicted 240): hop phase was ~29us/hop.
//          (a) k_fin dispatches removed -> finalize FUSED into k_acc via
//          last-arriving-block (atomic arrival counter; pure-atomic protocol:
//          partials via device-scope atomicAdd, read+reset via atomicExch,
//          threadfence+sync release; no spinning -> no deadlock). 23 -> 13
//          dispatches. (b) k_acc latency-bound at 3 blk/CU -> 8-edge ILP
//          batches: 2 uint4 index loads + 8 independent gathers in flight
//          before 8 LDS atomics.
// ANTI-LESSON (R8): cooperative grid.sync ~125us each on 8-XCD MI355X. Never.
// ANTI-LESSON (R9): MLP fused into scatter adds ~20us serial wave chains.
// ANTI-LESSON (R10): 1 block/bucket = parallelism cliff (196 blocks, 53us).

#define TPB  256
#define TSC  512             // scatter block threads
#define SBSH 10              // 1024 nodes per super-bucket
#define CAP1 37376           // bucket capacity (mean 32768, ~25 sigma; mult of 8)
#define EPT  8               // edges per thread in pass 1
#define CH   (TSC * EPT)     // 4096 edges per scatter block
#define CPB  8               // chunk-blocks per super-bucket in k_acc

// ---- MLP (thread per node, register-blocked) + bcursor/hcnt zeroing ----
__global__ void k_mlp(const float* __restrict__ x, const float* __restrict__ W1,
                      const float* __restrict__ b1, const float* __restrict__ W2,
                      const float* __restrict__ b2, const float* __restrict__ Wfc,
                      float* __restrict__ zarr, int* __restrict__ bcursor, int n) {
    int i = blockIdx.x * blockDim.x + threadIdx.x;
    if (i < 256) bcursor[i] = 0;       // [0,128) pass-1 cursors, [128,256) hop arrival counters
    if (i >= n) return;
    float xv = x[i];
    float h1[32];
#pragma unroll
    for (int j = 0; j < 32; j++)
        h1[j] = fmaxf(fmaf(xv, W1[j], b1[j]), 0.f);
    float z = 0.f;
#pragma unroll
    for (int fc = 0; fc < 4; fc++) {
        float acc[16];
#pragma unroll
        for (int f = 0; f < 16; f++) acc[f] = b2[fc * 16 + f];
#pragma unroll
        for (int j = 0; j < 32; j++) {
            float h = h1[j];
#pragma unroll
            for (int f = 0; f < 16; f++)
                acc[f] = fmaf(h, W2[j * 64 + fc * 16 + f], acc[f]);
        }
#pragma unroll
        for (int f = 0; f < 16; f++)
            z = fmaf(fmaxf(acc[f], 0.f), Wfc[fc * 16 + f], z);
    }
    zarr[i] = z;
}

// ---- Pass 1: bucket edges into 98 super-buckets, packed (src<<10)|dst10 ----
__global__ void __launch_bounds__(TSC)
k_scatter(const int* __restrict__ erow, const int* __restrict__ ecol,
          int* __restrict__ bcursor, unsigned int* __restrict__ ebuf1,
          int e, int nsb) {
    __shared__ int hist[128];
    __shared__ int base[128];
    int t = threadIdx.x;
    int s = blockIdx.x * CH;
    int r[EPT], c[EPT];

    if (t < 128) hist[t] = 0;
    __syncthreads();
#pragma unroll
    for (int j = 0; j < EPT; j++) {
        int i = s + j * TSC + t;
        bool ok = (i < e);
        c[j] = ok ? ecol[i] : -1;
        r[j] = ok ? erow[i] : 0;
        if (ok) atomicAdd(&hist[c[j] >> SBSH], 1);
    }
    __syncthreads();
    if (t < nsb) {
        int cc = hist[t];
        base[t] = cc ? atomicAdd(&bcursor[t], cc) : 0;
        hist[t] = 0;    // reuse as local cursor
    }
    __syncthreads();
#pragma unroll
    for (int j = 0; j < EPT; j++) {
        if (c[j] >= 0) {
            int b = c[j] >> SBSH;
            int pos = base[b] + atomicAdd(&hist[b], 1);
            if (pos < CAP1)
                ebuf1[(size_t)b * CAP1 + pos] =
                    ((unsigned int)r[j] << SBSH) | (unsigned int)(c[j] & 1023);
        }
    }
}

// ---- Pass 2: one 1024-thread block per super-bucket.
// (a) LDS histograms: 1024-bin dst (degrees) + 128-bin src-super-bucket.
// (b) 128-bin exclusive scan. (c) node init: nrm {1/d, sqrt(d)}, u0 = z/sqrt(d),
// out = b_fc + temp0*z; zero gacc; dummy slot u[n]=0. (d) scatter edges into
// ebuf2 sorted by src super-bucket; pad tail to x4 with sentinel (n<<10). ----
__global__ void __launch_bounds__(1024)
k_sub(const int* __restrict__ bcursor, const unsigned int* __restrict__ ebuf1,
      unsigned int* __restrict__ ebuf2, float2* __restrict__ nrm,
      const float* __restrict__ zarr, const float* __restrict__ temp,
      const float* __restrict__ bfc, float* __restrict__ u0,
      float* __restrict__ u1, float* __restrict__ gacc,
      float* __restrict__ out, int n) {
    __shared__ int hist[1024];
    __shared__ int h2[128];
    __shared__ int base2[128];
    __shared__ int carry;
    int b = blockIdx.x;
    int t = threadIdx.x;
    int lane = t & 63;
    int w = t >> 6;

    hist[t] = 0;
    if (t < 128) h2[t] = 0;
    __syncthreads();
    int cnt = min(bcursor[b], CAP1);
    size_t g = (size_t)b * CAP1;
    int last = cnt > 0 ? cnt - 1 : 0;
    for (int j = t; j < cnt; j += 4096) {
        int j1 = j + 1024, j2 = j + 2048, j3 = j + 3072;
        unsigned int p0 = ebuf1[g + j];
        unsigned int p1 = ebuf1[g + min(j1, last)];
        unsigned int p2 = ebuf1[g + min(j2, last)];
        unsigned int p3 = ebuf1[g + min(j3, last)];
        atomicAdd(&hist[p0 & 1023], 1);
        atomicAdd(&h2[p0 >> 20], 1);
        if (j1 < cnt) { atomicAdd(&hist[p1 & 1023], 1); atomicAdd(&h2[p1 >> 20], 1); }
        if (j2 < cnt) { atomicAdd(&hist[p2 & 1023], 1); atomicAdd(&h2[p2 >> 20], 1); }
        if (j3 < cnt) { atomicAdd(&hist[p3 & 1023], 1); atomicAdd(&h2[p3 >> 20], 1); }
    }
    __syncthreads();

    // exclusive scan of h2[0..127]; waves 0/1 carry real data
    int v128 = (t < 128) ? h2[t] : 0;
    int sv = v128;
#pragma unroll
    for (int o = 1; o < 64; o <<= 1) {
        int uu = __shfl_up(sv, o);
        if (lane >= o) sv += uu;
    }
    if (t == 63) carry = sv;          // total of bins 0..63
    __syncthreads();
    if (t < 128) {
        base2[t] = sv - v128 + (w == 1 ? carry : 0);
        h2[t] = 0;                    // reuse as cursor
    }

    // per-node init + gacc zero
    int node = (b << SBSH) + t;
    float dg = (float)(hist[t] + 1);  // +1 self-loop
    if (node < n) {
        float di = rsqrtf(dg);
        nrm[node] = make_float2(di * di, dg * di);   // {1/d, sqrt(d)}
        float z = zarr[node];
        u0[node] = di * z;
        out[node] = fmaf(temp[0], z, bfc[0]);
    }
    gacc[((size_t)b << SBSH) + t] = 0.f;
    if (b == 0 && t == 0) { u0[n] = 0.f; u1[n] = 0.f; }   // dummy gather slot
    __syncthreads();

    // scatter into src-super-bucket-sorted order
    for (int j = t; j < cnt; j += 4096) {
        int j1 = j + 1024, j2 = j + 2048, j3 = j + 3072;
        unsigned int p0 = ebuf1[g + j];
        unsigned int p1 = ebuf1[g + min(j1, last)];
        unsigned int p2 = ebuf1[g + min(j2, last)];
        unsigned int p3 = ebuf1[g + min(j3, last)];
        int q0 = base2[p0 >> 20] + atomicAdd(&h2[p0 >> 20], 1);
        ebuf2[g + q0] = p0;
        if (j1 < cnt) { int q = base2[p1 >> 20] + atomicAdd(&h2[p1 >> 20], 1); ebuf2[g + q] = p1; }
        if (j2 < cnt) { int q = base2[p2 >> 20] + atomicAdd(&h2[p2 >> 20], 1); ebuf2[g + q] = p2; }
        if (j3 < cnt) { int q = base2[p3 >> 20] + atomicAdd(&h2[p3 >> 20], 1); ebuf2[g + q] = p3; }
    }
    // pad bucket tail to multiple of 4 with sentinel edges -> u[n]=0, dst bits 0.
    if (t < ((4 - (cnt & 3)) & 3))
        ebuf2[g + cnt + t] = ((unsigned int)n) << SBSH;
}

// ---- Hop: 8 chunk-blocks per dst-bucket; 8-edge ILP batches (2 uint4 index
// loads + 8 independent gathers in flight, then 8 LDS atomics). Partials merge
// via device-scope atomicAdd into gacc; the LAST-arriving block of each bucket
// finalizes: sum=atomicExch(gacc,0) (coherent read+reset in one RMW),
// u_k = (1/d)(sum+u_{k-1}), out += temp[k]*sqrt(d)*u_k, reset arrival counter.
// No spin-waits -> schedule-safe. ----
__global__ void __launch_bounds__(256)
k_acc(const int* __restrict__ bcursor, const unsigned int* __restrict__ ebuf2,
      const float* __restrict__ u, float* __restrict__ gacc,
      int* __restrict__ hcnt, const float2* __restrict__ nrm,
      float* __restrict__ uout, float* __restrict__ out,
      const float* __restrict__ temp, int k, int n, int is_last) {
    __shared__ float acc[1024];
    __shared__ int amlast;
    int b = blockIdx.x / CPB;
    int chunk = blockIdx.x % CPB;
    int t = threadIdx.x;
#pragma unroll
    for (int i = t; i < 1024; i += 256) acc[i] = 0.f;
    __syncthreads();
    int cnt4 = (min(bcursor[b], CAP1) + 3) & ~3;          // sentinel-padded count
    int per = (((cnt4 + CPB - 1) / CPB) + 7) & ~7;        // mult of 8 -> aligned batches
    int s = chunk * per;
    int epos = min(s + per, cnt4);                        // mult of 4
    size_t g = (size_t)b * CAP1;
    const unsigned int SENT = ((unsigned int)n) << SBSH;
    const uint4 SENT4 = make_uint4(SENT, SENT, SENT, SENT);
    for (int i = s + 8 * t; i < epos; i += 2048) {
        uint4 pa = *(const uint4*)(ebuf2 + g + i);                        // 16B-aligned
        uint4 pb = (i + 4 < epos) ? *(const uint4*)(ebuf2 + g + i + 4) : SENT4;
        float v0 = u[pa.x >> 10];
        float v1 = u[pa.y >> 10];
        float v2 = u[pa.z >> 10];
        float v3 = u[pa.w >> 10];
        float v4 = u[pb.x >> 10];
        float v5 = u[pb.y >> 10];
        float v6 = u[pb.z >> 10];
        float v7 = u[pb.w >> 10];
        atomicAdd(&acc[pa.x & 1023], v0);
        atomicAdd(&acc[pa.y & 1023], v1);
        atomicAdd(&acc[pa.z & 1023], v2);
        atomicAdd(&acc[pa.w & 1023], v3);
        atomicAdd(&acc[pb.x & 1023], v4);
        atomicAdd(&acc[pb.y & 1023], v5);
        atomicAdd(&acc[pb.z & 1023], v6);
        atomicAdd(&acc[pb.w & 1023], v7);
    }
    __syncthreads();
    float* gb = gacc + ((size_t)b << SBSH);
#pragma unroll
    for (int i = t; i < 1024; i += 256)
        atomicAdd(&gb[i], acc[i]);

    // release: each thread waits for ITS atomics to be globally visible, then
    // block-sync so ALL threads' atomics are visible before the arrival mark.
    __threadfence();
    __syncthreads();
    if (t == 0)
        amlast = (atomicAdd(&hcnt[b], 1) == CPB - 1) ? 1 : 0;
    __syncthreads();
    if (amlast) {
        float tk = temp[k];
        int base = b << SBSH;
        for (int i = t; i < 1024; i += 256) {
            float ssum = atomicExch(&gb[i], 0.f);   // coherent read + reset for next hop
            int node = base + i;
            if (node < n) {
                float2 nv = nrm[node];              // {1/d, sqrt(d)}
                float uk = nv.x * (ssum + u[node]); // self-loop term + gathered sum
                if (!is_last) uout[node] = uk;
                out[node] = fmaf(tk * nv.y, uk, out[node]);
            }
        }
        if (t == 0) atomicExch(&hcnt[b], 0);        // rearm counter for next hop
    }
}

static inline size_t align256(size_t v) { return (v + 255) & ~(size_t)255; }

extern "C" void kernel_launch(void* const* d_in, const int* in_sizes, int n_in,
                              void* d_out, int out_size, void* d_ws, size_t ws_size,
                              hipStream_t stream) {
    const float* x    = (const float*)d_in[0];
    const int*   ei   = (const int*)d_in[1];
    const float* W1   = (const float*)d_in[2];
    const float* b1   = (const float*)d_in[3];
    const float* W2   = (const float*)d_in[4];
    const float* b2   = (const float*)d_in[5];
    const float* temp = (const float*)d_in[6];
    const float* Wfc  = (const float*)d_in[7];
    const float* bfc  = (const float*)d_in[8];

    const int n = in_sizes[0];        // 100000 nodes
    const int e = in_sizes[1] / 2;    // 3.2M edges
    const int K = in_sizes[6] - 1;    // 10 hops
    const int nsb = (n + (1 << SBSH) - 1) >> SBSH;   // 98 super-buckets

    const int* erow = ei;             // edge_index[0] = source
    const int* ecol = ei + e;         // edge_index[1] = target

    float* out = (float*)d_out;

    // workspace carve (~31.7 MB)
    char* ws = (char*)d_ws;
    int*          bcursor = (int*)ws;          ws += align256((size_t)256 * 4);
    unsigned int* ebuf1   = (unsigned int*)ws; ws += align256((size_t)nsb * CAP1 * 4);
    unsigned int* ebuf2   = (unsigned int*)ws; ws += align256((size_t)nsb * CAP1 * 4);
    float2*       nrm     = (float2*)ws;       ws += align256((size_t)n * 8);
    float*        zarr    = (float*)ws;        ws += align256((size_t)(n + 1) * 4);
    float*        u0      = (float*)ws;        ws += align256((size_t)(n + 1) * 4);
    float*        u1      = (float*)ws;        ws += align256((size_t)(n + 1) * 4);
    float*        gacc    = (float*)ws;        ws += align256((size_t)nsb * 1024 * 4);
    int*          hcnt    = bcursor + 128;     // hop arrival counters

    const int gM = (n + TPB - 1) / TPB;          // 391 MLP blocks
    const int gS = (e + CH - 1) / CH;            // 782 scatter blocks

    k_mlp<<<gM, TPB, 0, stream>>>(x, W1, b1, W2, b2, Wfc, zarr, bcursor, n);
    k_scatter<<<gS, TSC, 0, stream>>>(erow, ecol, bcursor, ebuf1, e, nsb);
    k_sub<<<nsb, 1024, 0, stream>>>(bcursor, ebuf1, ebuf2, nrm, zarr, temp, bfc,
                                    u0, u1, gacc, out, n);

    float* uin = u0;
    float* uout = u1;
    for (int k = 1; k <= K; k++) {
        k_acc<<<nsb * CPB, 256, 0, stream>>>(bcursor, ebuf2, uin, gacc, hcnt,
                                             nrm, uout, out, temp, k, n,
                                             (k == K) ? 1 : 0);
        float* t2 = uin; uin = uout; uout = t2;
    }
}

// Round 7
// 432.165 us; speedup vs baseline: 2.0471x; 2.0471x over previous
//
#include <hip/hip_runtime.h>

// GPR-GNN: out = b_fc + sum_k temp[k] * A_hat^k (MLP(x) @ W_fc)
// Trick 1: project features to scalar BEFORE propagation (linearity) -> 1 float/node.
// Trick 2: per-edge atomics are LDS-only (global RMW ~35B/edge, measured R2/R3).
// Trick 3: u-space propagation u_k = D^{-1/2} z_k -> per-edge work = gather+add.
// Trick 4: bucketing = two-level counting sort (98 super-buckets of 1024 nodes).
// Trick 6: PUSH-accumulate hops, edges sorted by src super-bucket within each
//          dst bucket -> gathers sweep u in small L1-resident windows.
// Trick 8 (R6, from R5 counters: k_acc 84.6us, VALUBusy 0.64%, HBM 1.8%):
//          device-scope fence/RMW protocol was the poison (threadfence = L2
//          writeback on 8-XCD non-coherent gfx950; 800K memory-side atomicAdd;
//          100K returning atomicExch). Fix: NO device-scope RMW/fence anywhere
//          in the hop. Each chunk-block stores its 1024 partials to a PRIVATE
//          gacc slice (plain coalesced stores, full overwrite -> no zeroing);
//          k_fin sums the 8 slices per node (coalesced L2 streams). Visibility
//          across dispatches = kernel-boundary ordering on the stream (the
//          supported pattern; no intra-dispatch communication anywhere).
// MEASURED (R5): preprocessing (mlp+scatter+sub) + overheads = ~35-40us total;
//          hop phase is everything else. Attribution now clean.
// ANTI-LESSON (R8): cooperative grid.sync ~125us each on 8-XCD MI355X. Never.
// ANTI-LESSON (R5): last-arriving-block finalize w/ threadfence: 84.6us/hop.
// ANTI-LESSON (R9): MLP fused into scatter adds ~20us serial wave chains.
// ANTI-LESSON (R10): 1 block/bucket = parallelism cliff (196 blocks, 53us).

#define TPB  256
#define TSC  512             // scatter block threads
#define SBSH 10              // 1024 nodes per super-bucket
#define CAP1 37376           // bucket capacity (mean 32768, ~25 sigma; mult of 8)
#define EPT  8               // edges per thread in pass 1
#define CH   (TSC * EPT)     // 4096 edges per scatter block
#define CPB  8               // chunk-blocks per super-bucket in k_acc

// ---- MLP (thread per node, register-blocked) + bcursor zeroing ----
__global__ void k_mlp(const float* __restrict__ x, const float* __restrict__ W1,
                      const float* __restrict__ b1, const float* __restrict__ W2,
                      const float* __restrict__ b2, const float* __restrict__ Wfc,
                      float* __restrict__ zarr, int* __restrict__ bcursor, int n) {
    int i = blockIdx.x * blockDim.x + threadIdx.x;
    if (i < 128) bcursor[i] = 0;
    if (i >= n) return;
    float xv = x[i];
    float h1[32];
#pragma unroll
    for (int j = 0; j < 32; j++)
        h1[j] = fmaxf(fmaf(xv, W1[j], b1[j]), 0.f);
    float z = 0.f;
#pragma unroll
    for (int fc = 0; fc < 4; fc++) {
        float acc[16];
#pragma unroll
        for (int f = 0; f < 16; f++) acc[f] = b2[fc * 16 + f];
#pragma unroll
        for (int j = 0; j < 32; j++) {
            float h = h1[j];
#pragma unroll
            for (int f = 0; f < 16; f++)
                acc[f] = fmaf(h, W2[j * 64 + fc * 16 + f], acc[f]);
        }
#pragma unroll
        for (int f = 0; f < 16; f++)
            z = fmaf(fmaxf(acc[f], 0.f), Wfc[fc * 16 + f], z);
    }
    zarr[i] = z;
}

// ---- Pass 1: bucket edges into 98 super-buckets, packed (src<<10)|dst10 ----
__global__ void __launch_bounds__(TSC)
k_scatter(const int* __restrict__ erow, const int* __restrict__ ecol,
          int* __restrict__ bcursor, unsigned int* __restrict__ ebuf1,
          int e, int nsb) {
    __shared__ int hist[128];
    __shared__ int base[128];
    int t = threadIdx.x;
    int s = blockIdx.x * CH;
    int r[EPT], c[EPT];

    if (t < 128) hist[t] = 0;
    __syncthreads();
#pragma unroll
    for (int j = 0; j < EPT; j++) {
        int i = s + j * TSC + t;
        bool ok = (i < e);
        c[j] = ok ? ecol[i] : -1;
        r[j] = ok ? erow[i] : 0;
        if (ok) atomicAdd(&hist[c[j] >> SBSH], 1);
    }
    __syncthreads();
    if (t < nsb) {
        int cc = hist[t];
        base[t] = cc ? atomicAdd(&bcursor[t], cc) : 0;
        hist[t] = 0;    // reuse as local cursor
    }
    __syncthreads();
#pragma unroll
    for (int j = 0; j < EPT; j++) {
        if (c[j] >= 0) {
            int b = c[j] >> SBSH;
            int pos = base[b] + atomicAdd(&hist[b], 1);
            if (pos < CAP1)
                ebuf1[(size_t)b * CAP1 + pos] =
                    ((unsigned int)r[j] << SBSH) | (unsigned int)(c[j] & 1023);
        }
    }
}

// ---- Pass 2: one 1024-thread block per super-bucket.
// (a) LDS histograms: 1024-bin dst (degrees) + 128-bin src-super-bucket.
// (b) 128-bin exclusive scan. (c) node init: nrm {1/d, sqrt(d)}, u0 = z/sqrt(d),
// out = b_fc + temp0*z; dummy slot u[n]=0. (d) scatter edges into ebuf2 sorted
// by src super-bucket; pad tail to x4 with sentinel (n<<10). ----
__global__ void __launch_bounds__(1024)
k_sub(const int* __restrict__ bcursor, const unsigned int* __restrict__ ebuf1,
      unsigned int* __restrict__ ebuf2, float2* __restrict__ nrm,
      const float* __restrict__ zarr, const float* __restrict__ temp,
      const float* __restrict__ bfc, float* __restrict__ u0,
      float* __restrict__ u1, float* __restrict__ out, int n) {
    __shared__ int hist[1024];
    __shared__ int h2[128];
    __shared__ int base2[128];
    __shared__ int carry;
    int b = blockIdx.x;
    int t = threadIdx.x;
    int lane = t & 63;
    int w = t >> 6;

    hist[t] = 0;
    if (t < 128) h2[t] = 0;
    __syncthreads();
    int cnt = min(bcursor[b], CAP1);
    size_t g = (size_t)b * CAP1;
    int last = cnt > 0 ? cnt - 1 : 0;
    for (int j = t; j < cnt; j += 4096) {
        int j1 = j + 1024, j2 = j + 2048, j3 = j + 3072;
        unsigned int p0 = ebuf1[g + j];
        unsigned int p1 = ebuf1[g + min(j1, last)];
        unsigned int p2 = ebuf1[g + min(j2, last)];
        unsigned int p3 = ebuf1[g + min(j3, last)];
        atomicAdd(&hist[p0 & 1023], 1);
        atomicAdd(&h2[p0 >> 20], 1);
        if (j1 < cnt) { atomicAdd(&hist[p1 & 1023], 1); atomicAdd(&h2[p1 >> 20], 1); }
        if (j2 < cnt) { atomicAdd(&hist[p2 & 1023], 1); atomicAdd(&h2[p2 >> 20], 1); }
        if (j3 < cnt) { atomicAdd(&hist[p3 & 1023], 1); atomicAdd(&h2[p3 >> 20], 1); }
    }
    __syncthreads();

    // exclusive scan of h2[0..127]; waves 0/1 carry real data
    int v128 = (t < 128) ? h2[t] : 0;
    int sv = v128;
#pragma unroll
    for (int o = 1; o < 64; o <<= 1) {
        int uu = __shfl_up(sv, o);
        if (lane >= o) sv += uu;
    }
    if (t == 63) carry = sv;          // total of bins 0..63
    __syncthreads();
    if (t < 128) {
        base2[t] = sv - v128 + (w == 1 ? carry : 0);
        h2[t] = 0;                    // reuse as cursor
    }

    // per-node init
    int node = (b << SBSH) + t;
    float dg = (float)(hist[t] + 1);  // +1 self-loop
    if (node < n) {
        float di = rsqrtf(dg);
        nrm[node] = make_float2(di * di, dg * di);   // {1/d, sqrt(d)}
        float z = zarr[node];
        u0[node] = di * z;
        out[node] = fmaf(temp[0], z, bfc[0]);
    }
    if (b == 0 && t == 0) { u0[n] = 0.f; u1[n] = 0.f; }   // dummy gather slot
    __syncthreads();

    // scatter into src-super-bucket-sorted order
    for (int j = t; j < cnt; j += 4096) {
        int j1 = j + 1024, j2 = j + 2048, j3 = j + 3072;
        unsigned int p0 = ebuf1[g + j];
        unsigned int p1 = ebuf1[g + min(j1, last)];
        unsigned int p2 = ebuf1[g + min(j2, last)];
        unsigned int p3 = ebuf1[g + min(j3, last)];
        int q0 = base2[p0 >> 20] + atomicAdd(&h2[p0 >> 20], 1);
        ebuf2[g + q0] = p0;
        if (j1 < cnt) { int q = base2[p1 >> 20] + atomicAdd(&h2[p1 >> 20], 1); ebuf2[g + q] = p1; }
        if (j2 < cnt) { int q = base2[p2 >> 20] + atomicAdd(&h2[p2 >> 20], 1); ebuf2[g + q] = p2; }
        if (j3 < cnt) { int q = base2[p3 >> 20] + atomicAdd(&h2[p3 >> 20], 1); ebuf2[g + q] = p3; }
    }
    // pad bucket tail to multiple of 4 with sentinel edges -> u[n]=0, dst bits 0.
    if (t < ((4 - (cnt & 3)) & 3))
        ebuf2[g + cnt + t] = ((unsigned int)n) << SBSH;
}

// ---- Hop accumulate: 8 chunk-blocks per dst-bucket; 8-edge ILP batches
// (2 uint4 index loads + 8 independent gathers in flight, then 8 LDS atomics).
// Epilogue: plain coalesced stores of the 1024 partials to this block's
// PRIVATE gacc slice. No global atomics, no fences, no zero-init needed. ----
__global__ void __launch_bounds__(256)
k_acc(const int* __restrict__ bcursor, const unsigned int* __restrict__ ebuf2,
      const float* __restrict__ u, float* __restrict__ gacc) {
    __shared__ float acc[1024];
    int b = blockIdx.x / CPB;
    int chunk = blockIdx.x % CPB;
    int t = threadIdx.x;
#pragma unroll
    for (int i = t; i < 1024; i += 256) acc[i] = 0.f;
    __syncthreads();
    int cnt4 = (min(bcursor[b], CAP1) + 3) & ~3;          // sentinel-padded count
    int per = (((cnt4 + CPB - 1) / CPB) + 7) & ~7;        // mult of 8 -> aligned batches
    int s = chunk * per;
    int epos = min(s + per, cnt4);                        // mult of 4
    size_t g = (size_t)b * CAP1;
    for (int i = s + 8 * t; i < epos; i += 2048) {
        uint4 pa = *(const uint4*)(ebuf2 + g + i);                        // 16B-aligned
        bool hb = (i + 4 < epos);
        uint4 pb = hb ? *(const uint4*)(ebuf2 + g + i + 4) : pa;
        float v0 = u[pa.x >> 10];
        float v1 = u[pa.y >> 10];
        float v2 = u[pa.z >> 10];
        float v3 = u[pa.w >> 10];
        float v4 = u[pb.x >> 10];
        float v5 = u[pb.y >> 10];
        float v6 = u[pb.z >> 10];
        float v7 = u[pb.w >> 10];
        atomicAdd(&acc[pa.x & 1023], v0);
        atomicAdd(&acc[pa.y & 1023], v1);
        atomicAdd(&acc[pa.z & 1023], v2);
        atomicAdd(&acc[pa.w & 1023], v3);
        if (hb) {
            atomicAdd(&acc[pb.x & 1023], v4);
            atomicAdd(&acc[pb.y & 1023], v5);
            atomicAdd(&acc[pb.z & 1023], v6);
            atomicAdd(&acc[pb.w & 1023], v7);
        }
    }
    __syncthreads();
    // private slice: full overwrite, coalesced dword stores
    float* gb = gacc + (((size_t)(b * CPB + chunk)) << SBSH);
#pragma unroll
    for (int i = t; i < 1024; i += 256)
        gb[i] = acc[i];
}

// ---- Hop finalize: sum the CPB private partials per node; u_k =
// (1/d)*(sum + u_{k-1}); out += temp[k]*sqrt(d)*u_k. All plain loads/stores. ----
__global__ void k_fin(const float* __restrict__ gacc, const float2* __restrict__ nrm,
                      const float* __restrict__ uin, float* __restrict__ uout,
                      float* __restrict__ out, const float* __restrict__ temp,
                      int k, int n, int is_last) {
    int i = blockIdx.x * blockDim.x + threadIdx.x;
    if (i >= n) return;
    int b = i >> SBSH;
    int sl = i & ((1 << SBSH) - 1);
    const float* gp = gacc + (((size_t)b * CPB) << SBSH) + sl;
    float s = 0.f;
#pragma unroll
    for (int c = 0; c < CPB; c++)
        s += gp[c << SBSH];
    float2 nv = nrm[i];
    float uk = nv.x * (s + uin[i]);     // self-loop term + gathered sum
    if (!is_last) uout[i] = uk;
    out[i] = fmaf(temp[k] * nv.y, uk, out[i]);
}

static inline size_t align256(size_t v) { return (v + 255) & ~(size_t)255; }

extern "C" void kernel_launch(void* const* d_in, const int* in_sizes, int n_in,
                              void* d_out, int out_size, void* d_ws, size_t ws_size,
                              hipStream_t stream) {
    const float* x    = (const float*)d_in[0];
    const int*   ei   = (const int*)d_in[1];
    const float* W1   = (const float*)d_in[2];
    const float* b1   = (const float*)d_in[3];
    const float* W2   = (const float*)d_in[4];
    const float* b2   = (const float*)d_in[5];
    const float* temp = (const float*)d_in[6];
    const float* Wfc  = (const float*)d_in[7];
    const float* bfc  = (const float*)d_in[8];

    const int n = in_sizes[0];        // 100000 nodes
    const int e = in_sizes[1] / 2;    // 3.2M edges
    const int K = in_sizes[6] - 1;    // 10 hops
    const int nsb = (n + (1 << SBSH) - 1) >> SBSH;   // 98 super-buckets

    const int* erow = ei;             // edge_index[0] = source
    const int* ecol = ei + e;         // edge_index[1] = target

    float* out = (float*)d_out;

    // workspace carve (~34 MB)
    char* ws = (char*)d_ws;
    int*          bcursor = (int*)ws;          ws += align256((size_t)128 * 4);
    unsigned int* ebuf1   = (unsigned int*)ws; ws += align256((size_t)nsb * CAP1 * 4);
    unsigned int* ebuf2   = (unsigned int*)ws; ws += align256((size_t)nsb * CAP1 * 4);
    float2*       nrm     = (float2*)ws;       ws += align256((size_t)n * 8);
    float*        zarr    = (float*)ws;        ws += align256((size_t)(n + 1) * 4);
    float*        u0      = (float*)ws;        ws += align256((size_t)(n + 1) * 4);
    float*        u1      = (float*)ws;        ws += align256((size_t)(n + 1) * 4);
    float*        gacc    = (float*)ws;        ws += align256((size_t)nsb * CPB * 1024 * 4);

    const int gM = (n + TPB - 1) / TPB;          // 391 MLP blocks
    const int gS = (e + CH - 1) / CH;            // 782 scatter blocks
    const int gF = (n + TPB - 1) / TPB;          // 391 finalize blocks

    k_mlp<<<gM, TPB, 0, stream>>>(x, W1, b1, W2, b2, Wfc, zarr, bcursor, n);
    k_scatter<<<gS, TSC, 0, stream>>>(erow, ecol, bcursor, ebuf1, e, nsb);
    k_sub<<<nsb, 1024, 0, stream>>>(bcursor, ebuf1, ebuf2, nrm, zarr, temp, bfc,
                                    u0, u1, out, n);

    float* uin = u0;
    float* uout = u1;
    for (int k = 1; k <= K; k++) {
        k_acc<<<nsb * CPB, 256, 0, stream>>>(bcursor, ebuf2, uin, gacc);
        k_fin<<<gF, TPB, 0, stream>>>(gacc, nrm, uin, uout, out, temp,
                                      k, n, (k == K) ? 1 : 0);
        float* t2 = uin; uin = uout; uout = t2;
    }
}

// Round 13
// 332.797 us; speedup vs baseline: 2.6583x; 1.2986x over previous
//
#include <hip/hip_runtime.h>

// GPR-GNN: out = b_fc + sum_k temp[k] * A_hat^k (MLP(x) @ W_fc)
// Trick 1: project features to scalar BEFORE propagation (linearity) -> 1 float/node.
// Trick 2: per-edge GLOBAL atomics cost ~35B memory-side RMW (measured R2/R3)
//          -> per-edge atomics are LDS-only.
// Trick 3: u-space propagation u_k = D^{-1/2} z_k -> per-edge work is one
//          unweighted gather+add; CSR is row indices only.
// Trick 4: CSR build = two-level counting sort (98 super-buckets of 1024 nodes;
//          pass-1 runs ~600B >> 128B line -> write amp ~1; pass-2 in an
//          L2-resident window). Scatter: 512 thr x 8 edges (serial LDS-atomic
//          chain halved vs 256x16 -- R9 showed scatter latency-bound).
// Trick 5: segments padded to x4; pads index dummy slot n (u[n]=0) -> hop does
//          ONE aligned uint4 index load + 4 independent gathers per thread.
// MEASURED FLOOR (R7/R9/R10): gather hop ~20us = L2-line bound (3.3M x 128B
//          = 422MB L2 traffic / ~25TB/s). ILP tweaks neutral; LDS-tiled SpMV
//          (R10) trades traffic for a 196-block parallelism cliff (53us). Keep
//          the gather.
// SESSION NOTE (R13): push-accumulate redesigns (R4-R12) measured 417-885us
//          (CPB=8 latency-bound at 22% occupancy; fused-finalize fence poison);
//          the CPB=24 occupancy fix never got a measurement through infra.
//          Reverting to this verified 332us pull kernel per the R12 fallback.
// ANTI-LESSON (R8): cooperative grid.sync ~125us each on 8-XCD MI355X. Never.
// ANTI-LESSON (R9): MLP fused into scatter adds ~20us serial wave chains ->
//          separate thread-per-node register-blocked MLP.

#define TPB  256
#define TSC  512             // scatter block threads
#define SBSH 10              // 1024 nodes per super-bucket
#define CAP1 37376           // capacity (mean padded ~34200, ~16 sigma; mult of 4)
#define EPT  8               // edges per thread in pass 1
#define CH   (TSC * EPT)     // 4096 edges per scatter block

// ---- MLP (thread per node, register-blocked) + bcursor zeroing ----
__global__ void k_mlp(const float* __restrict__ x, const float* __restrict__ W1,
                      const float* __restrict__ b1, const float* __restrict__ W2,
                      const float* __restrict__ b2, const float* __restrict__ Wfc,
                      float* __restrict__ zarr, int* __restrict__ bcursor, int n) {
    int i = blockIdx.x * blockDim.x + threadIdx.x;
    if (i < 128) bcursor[i] = 0;
    if (i >= n) return;
    float xv = x[i];
    float h1[32];
#pragma unroll
    for (int j = 0; j < 32; j++)
        h1[j] = fmaxf(fmaf(xv, W1[j], b1[j]), 0.f);
    float z = 0.f;
#pragma unroll
    for (int fc = 0; fc < 4; fc++) {
        float acc[16];
#pragma unroll
        for (int f = 0; f < 16; f++) acc[f] = b2[fc * 16 + f];
#pragma unroll
        for (int j = 0; j < 32; j++) {
            float h = h1[j];
#pragma unroll
            for (int f = 0; f < 16; f++)
                acc[f] = fmaf(h, W2[j * 64 + fc * 16 + f], acc[f]);
        }
#pragma unroll
        for (int f = 0; f < 16; f++)
            z = fmaf(fmaxf(acc[f], 0.f), Wfc[fc * 16 + f], z);
    }
    zarr[i] = z;
}

// ---- Pass 1: bucket edges into 98 super-buckets, packed (row<<10)|tgt10 ----
__global__ void __launch_bounds__(TSC)
k_scatter(const int* __restrict__ erow, const int* __restrict__ ecol,
          int* __restrict__ bcursor, unsigned int* __restrict__ ebuf1,
          int e, int nsb) {
    __shared__ int hist[128];
    __shared__ int base[128];
    int t = threadIdx.x;
    int s = blockIdx.x * CH;
    int r[EPT], c[EPT];

    if (t < 128) hist[t] = 0;
    __syncthreads();
#pragma unroll
    for (int j = 0; j < EPT; j++) {
        int i = s + j * TSC + t;
        bool ok = (i < e);
        c[j] = ok ? ecol[i] : -1;
        r[j] = ok ? erow[i] : 0;
        if (ok) atomicAdd(&hist[c[j] >> SBSH], 1);
    }
    __syncthreads();
    if (t < nsb) {
        int cc = hist[t];
        base[t] = cc ? atomicAdd(&bcursor[t], cc) : 0;
        hist[t] = 0;    // reuse as local cursor
    }
    __syncthreads();
#pragma unroll
    for (int j = 0; j < EPT; j++) {
        if (c[j] >= 0) {
            int b = c[j] >> SBSH;
            int pos = base[b] + atomicAdd(&hist[b], 1);
            if (pos < CAP1)
                ebuf1[(size_t)b * CAP1 + pos] =
                    ((unsigned int)r[j] << SBSH) | (unsigned int)(c[j] & 1023);
        }
    }
}

// ---- Pass 2: one 1024-thread block per super-bucket. LDS 1024-bin histogram,
// wave-shuffle scan over PADDED (x4) degrees, scatter into the bucket's
// L2-resident window, pads -> dummy index n. Fused u0/out init. ----
__global__ void __launch_bounds__(1024)
k_sub(const int* __restrict__ bcursor, const unsigned int* __restrict__ ebuf1,
      unsigned int* __restrict__ csr, int2* __restrict__ rs_re,
      float2* __restrict__ nrm, const float* __restrict__ zarr,
      const float* __restrict__ temp, const float* __restrict__ bfc,
      float* __restrict__ u0, float* __restrict__ u1,
      float* __restrict__ out, int n) {
    __shared__ int hist[1024];
    __shared__ int wsum[16];
    int b = blockIdx.x;
    int t = threadIdx.x;
    int lane = t & 63;
    int w = t >> 6;

    hist[t] = 0;
    __syncthreads();
    int cnt = min(bcursor[b], CAP1);
    size_t g = (size_t)b * CAP1;
    int last = cnt > 0 ? cnt - 1 : 0;
    for (int j = t; j < cnt; j += 4096) {
        int j1 = j + 1024, j2 = j + 2048, j3 = j + 3072;
        unsigned int p0 = ebuf1[g + j];
        unsigned int p1 = ebuf1[g + min(j1, last)];
        unsigned int p2 = ebuf1[g + min(j2, last)];
        unsigned int p3 = ebuf1[g + min(j3, last)];
        atomicAdd(&hist[p0 & 1023], 1);
        if (j1 < cnt) atomicAdd(&hist[p1 & 1023], 1);
        if (j2 < cnt) atomicAdd(&hist[p2 & 1023], 1);
        if (j3 < cnt) atomicAdd(&hist[p3 & 1023], 1);
    }
    __syncthreads();

    int deg = hist[t];
    int pdeg = (deg + 3) & ~3;          // padded to multiple of 4 (16B uint4)
    int v = pdeg;
#pragma unroll
    for (int o = 1; o < 64; o <<= 1) {
        int u = __shfl_up(v, o);
        if (lane >= o) v += u;
    }
    if (lane == 63) wsum[w] = v;
    __syncthreads();
    if (w == 0) {
        int sv = (lane < 16) ? wsum[lane] : 0;
#pragma unroll
        for (int o = 1; o < 16; o <<= 1) {
            int u = __shfl_up(sv, o);
            if (lane >= o) sv += u;
        }
        if (lane < 16) wsum[lane] = sv;
    }
    __syncthreads();
    int pexcl = v - pdeg + (w > 0 ? wsum[w - 1] : 0);

    int node = (b << SBSH) + t;
    if (node < n) {
        int bs = (int)g + pexcl;
        rs_re[node] = make_int2(bs, bs + pdeg);
        float d = (float)(deg + 1);     // +1 self-loop
        float di = rsqrtf(d);
        nrm[node] = make_float2(di * di, d * di);   // {dinv2, sqrt(d)}
        float z = zarr[node];
        u0[node] = di * z;
        out[node] = fmaf(temp[0], z, bfc[0]);
    }
    if (b == 0 && t == 0) { u0[n] = 0.f; u1[n] = 0.f; }   // dummy gather slot
    __syncthreads();
    hist[t] = pexcl;                     // per-sub cursor
    __syncthreads();
    for (int j = t; j < cnt; j += 4096) {
        int j1 = j + 1024, j2 = j + 2048, j3 = j + 3072;
        unsigned int p0 = ebuf1[g + j];
        unsigned int p1 = ebuf1[g + min(j1, last)];
        unsigned int p2 = ebuf1[g + min(j2, last)];
        unsigned int p3 = ebuf1[g + min(j3, last)];
        int pos0 = atomicAdd(&hist[p0 & 1023], 1);
        csr[g + pos0] = p0 >> SBSH;
        if (j1 < cnt) { int p = atomicAdd(&hist[p1 & 1023], 1); csr[g + p] = p1 >> SBSH; }
        if (j2 < cnt) { int p = atomicAdd(&hist[p2 & 1023], 1); csr[g + p] = p2 >> SBSH; }
        if (j3 < cnt) { int p = atomicAdd(&hist[p3 & 1023], 1); csr[g + p] = p3 >> SBSH; }
    }
    __syncthreads();
    // pad fill: entries [pexcl+deg, pexcl+pdeg) -> dummy index n
    for (int p = pexcl + deg; p < pexcl + pdeg; p++)
        csr[g + p] = (unsigned int)n;
}

// ---- Hop k: 8 threads/node, one aligned uint4 index load + 4 independent
// gathers per thread. u_k = dinv2*(u_{k-1}+sum); out += temp[k]*sqrt(d)*u_k ----
__global__ void k_hop(const int2* __restrict__ rs_re, const uint4* __restrict__ csr4,
                      const float2* __restrict__ nrm,
                      const float* __restrict__ uprev, float* __restrict__ ucur,
                      float* __restrict__ out, const float* __restrict__ temp,
                      int k, int n, int is_last) {
    int tid = blockIdx.x * blockDim.x + threadIdx.x;
    int node = tid >> 3;
    int sub = tid & 7;
    if (node >= n) return;
    int2 se = rs_re[node];
    int s4 = se.x >> 2;                  // uint4 index of segment start
    int e4 = se.y >> 2;
    float sum = (sub == 0) ? uprev[node] : 0.f;   // self-loop term
    for (int i4 = s4 + sub; i4 < e4; i4 += 8) {
        uint4 a = csr4[i4];
        float v0 = uprev[a.x];
        float v1 = uprev[a.y];
        float v2 = uprev[a.z];
        float v3 = uprev[a.w];
        sum += (v0 + v1) + (v2 + v3);
    }
    sum += __shfl_xor(sum, 1);
    sum += __shfl_xor(sum, 2);
    sum += __shfl_xor(sum, 4);
    if (sub == 0) {
        float2 nv = nrm[node];           // {dinv2, sqrt(d)}
        float u = nv.x * sum;
        if (!is_last) ucur[node] = u;
        out[node] = fmaf(temp[k] * nv.y, u, out[node]);
    }
}

static inline size_t align256(size_t v) { return (v + 255) & ~(size_t)255; }

extern "C" void kernel_launch(void* const* d_in, const int* in_sizes, int n_in,
                              void* d_out, int out_size, void* d_ws, size_t ws_size,
                              hipStream_t stream) {
    const float* x    = (const float*)d_in[0];
    const int*   ei   = (const int*)d_in[1];
    const float* W1   = (const float*)d_in[2];
    const float* b1   = (const float*)d_in[3];
    const float* W2   = (const float*)d_in[4];
    const float* b2   = (const float*)d_in[5];
    const float* temp = (const float*)d_in[6];
    const float* Wfc  = (const float*)d_in[7];
    const float* bfc  = (const float*)d_in[8];

    const int n = in_sizes[0];        // 100000 nodes
    const int e = in_sizes[1] / 2;    // 3.2M edges
    const int K = in_sizes[6] - 1;    // 10 hops
    const int nsb = (n + (1 << SBSH) - 1) >> SBSH;   // 98 super-buckets

    const int* erow = ei;             // edge_index[0] = source
    const int* ecol = ei + e;         // edge_index[1] = target

    float* out = (float*)d_out;

    // workspace carve
    char* ws = (char*)d_ws;
    int*          bcursor = (int*)ws;          ws += align256((size_t)128 * 4);
    unsigned int* ebuf1   = (unsigned int*)ws; ws += align256((size_t)nsb * CAP1 * 4);
    unsigned int* csr     = (unsigned int*)ws; ws += align256((size_t)nsb * CAP1 * 4);
    int2*         rs_re   = (int2*)ws;         ws += align256((size_t)n * 8);
    float2*       nrm     = (float2*)ws;       ws += align256((size_t)n * 8);
    float*        zarr    = (float*)ws;        ws += align256((size_t)(n + 1) * 4);
    float*        u0      = (float*)ws;        ws += align256((size_t)(n + 1) * 4);
    float*        u1      = (float*)ws;        ws += align256((size_t)(n + 1) * 4);

    const int gM = (n + TPB - 1) / TPB;          // 391 MLP blocks
    const int gS = (e + CH - 1) / CH;            // 782 scatter blocks
    const int gH = (8 * n + TPB - 1) / TPB;      // 8 threads/node hops

    k_mlp<<<gM, TPB, 0, stream>>>(x, W1, b1, W2, b2, Wfc, zarr, bcursor, n);
    k_scatter<<<gS, TSC, 0, stream>>>(erow, ecol, bcursor, ebuf1, e, nsb);
    k_sub<<<nsb, 1024, 0, stream>>>(bcursor, ebuf1, csr, rs_re, nrm,
                                    zarr, temp, bfc, u0, u1, out, n);

    float* uin = u0;
    float* uout = u1;
    for (int k = 1; k <= K; k++) {
        k_hop<<<gH, TPB, 0, stream>>>(rs_re, (const uint4*)csr, nrm, uin, uout,
                                      out, temp, k, n, (k == K) ? 1 : 0);
        float* t2 = uin; uin = uout; uout = t2;
    }
}